// Round 2
// baseline (207.526 us; speedup 1.0000x reference)
//
#include <hip/hip_runtime.h>
#include <math.h>

// Problem constants (fixed by setup_inputs)
#define Bn 4
#define Hn 8
#define Sn 4096
#define Dn 256
#define Mn 256
#define BSn (Bn*Sn)          // 16384 rows
#define LN_EPS 1e-5f
#define KEPS 1e-4f
#define DATA_NORM 0.25f      // 256^-0.25
#define RATIO 0.0625f        // 256^-0.5

typedef short s8v __attribute__((ext_vector_type(8)));   // 8 bf16 (4 VGPRs)
typedef short s4v __attribute__((ext_vector_type(4)));
typedef float f4v __attribute__((ext_vector_type(4)));   // MFMA acc

#define BSTR 72   // bf16 BK=64 LDS row stride, shorts (144 B rows -> 2-way bank aliasing, free)

// ---------- bf16 helpers (manual RNE) ----------
__device__ __forceinline__ unsigned short f2bf(float x) {
    unsigned u = __float_as_uint(x);
    u += 0x7FFFu + ((u >> 16) & 1u);
    return (unsigned short)(u >> 16);
}
__device__ __forceinline__ float bf2f(unsigned short h) {
    return __uint_as_float(((unsigned)h) << 16);
}
// monotone float<->uint encoding for atomicMax rowmax (0 acts as sentinel below all data)
__device__ __forceinline__ unsigned enc_f(float f) {
    unsigned u = __float_as_uint(f);
    return (u & 0x80000000u) ? ~u : (u | 0x80000000u);
}
__device__ __forceinline__ float dec_f(unsigned u) {
    unsigned b = (u & 0x80000000u) ? (u ^ 0x80000000u) : ~u;
    return __uint_as_float(b);
}

// ---------- 1. LayerNorm STATS ONLY (wave-per-row): (mu, rstd) + diag + mxqI zero ----------
// No normalized tensor is materialized; consumers apply LN inline (affine per-row).
// Extra blocks (>= BSn/4): split P into hi/lo bf16, zero KSUM, zero mxkI.
__global__ __launch_bounds__(256) void k_ln(const float* __restrict__ X,
                                            const float* __restrict__ gamma,
                                            const float* __restrict__ beta,
                                            const float* __restrict__ P,
                                            float2* __restrict__ stats,
                                            float* __restrict__ diag,
                                            unsigned* __restrict__ mxqI,
                                            unsigned short* __restrict__ Ph,
                                            unsigned short* __restrict__ Pl,
                                            float* __restrict__ KSUM,
                                            unsigned* __restrict__ mxkI) {
    if (blockIdx.x >= BSn / 4) {
        const int e = blockIdx.x - BSn / 4;
        if (e < 32) {
            // split P into hi/lo bf16
            const int i = (e * 256 + threadIdx.x) * 8;
            float v[8];
            *(float4*)&v[0] = *(const float4*)&P[i];
            *(float4*)&v[4] = *(const float4*)&P[i + 4];
            s8v hh, ll;
            #pragma unroll
            for (int q = 0; q < 8; q++) {
                unsigned short h = f2bf(v[q]);
                hh[q] = (short)h;
                ll[q] = (short)f2bf(v[q] - bf2f(h));
            }
            *(s8v*)&Ph[i] = hh;
            *(s8v*)&Pl[i] = ll;
        } else {
            KSUM[threadIdx.x]       = 0.0f;
            KSUM[threadIdx.x + 256] = 0.0f;
            KSUM[threadIdx.x + 512] = 0.0f;
            KSUM[threadIdx.x + 768] = 0.0f;
            if (threadIdx.x < 4) mxkI[threadIdx.x] = 0u;
        }
        return;
    }
    const int w = threadIdx.x >> 6, l = threadIdx.x & 63;
    const int row = blockIdx.x * 4 + w;
    float4 x = *(const float4*)&X[(size_t)row * Dn + l * 4];
    float s = x.x + x.y + x.z + x.w;
    #pragma unroll
    for (int o = 32; o > 0; o >>= 1) s += __shfl_xor(s, o);
    const float mean = s * (1.0f / Dn);
    float xn[4] = {x.x - mean, x.y - mean, x.z - mean, x.w - mean};
    float vs = xn[0] * xn[0] + xn[1] * xn[1] + xn[2] * xn[2] + xn[3] * xn[3];
    #pragma unroll
    for (int o = 32; o > 0; o >>= 1) vs += __shfl_xor(vs, o);
    const float rs = rsqrtf(vs * (1.0f / Dn) + LN_EPS);
    float4 g = *(const float4*)&gamma[l * 4];
    float4 bt = *(const float4*)&beta[l * 4];
    xn[0] = xn[0] * rs * g.x + bt.x;
    xn[1] = xn[1] * rs * g.y + bt.y;
    xn[2] = xn[2] * rs * g.z + bt.z;
    xn[3] = xn[3] * rs * g.w + bt.w;
    float d2 = xn[0] * xn[0] + xn[1] * xn[1] + xn[2] * xn[2] + xn[3] * xn[3];
    #pragma unroll
    for (int o = 32; o > 0; o >>= 1) d2 += __shfl_xor(d2, o);
    if (l == 0) {
        stats[row] = make_float2(mean, rs);
        diag[row] = 0.03125f * d2;
        mxqI[row] = 0u;
    }
}

// ---------- 2. GEMM1 (split fp32, inline-LN A): PD = 0.25*LN(X)@P^T + rowmax + batchmax ----------
// 64x128 tile, BK=64, grid 512 (2 blocks/CU). A-staging applies LN affine + hi/lo split on the fly.
__global__ __launch_bounds__(256, 2) void k_gemm1(const float* __restrict__ X,
                                                  const float2* __restrict__ stats,
                                                  const float* __restrict__ gamma,
                                                  const float* __restrict__ beta,
                                                  const unsigned short* __restrict__ Ph,
                                                  const unsigned short* __restrict__ Pl,
                                                  float* __restrict__ PD,
                                                  unsigned* __restrict__ mxqI,
                                                  unsigned* __restrict__ mxkI) {
    __shared__ unsigned short Ah[64 * BSTR], Al[64 * BSTR];
    __shared__ unsigned short Bh[128 * BSTR], Bl[128 * BSTR];
    __shared__ float bmS[4];
    const int t = threadIdx.x, lane = t & 63, w = t >> 6;
    const int wr = w >> 1, wc = w & 1, quad = lane >> 4, cc = lane & 15;
    const int r0 = blockIdx.x * 64, m0 = blockIdx.y * 128;
    const int ar0 = t >> 3, ac8 = (t & 7) * 8;
    const float2 st0 = stats[r0 + ar0];
    const float2 st1 = stats[r0 + ar0 + 32];
    f4v acc[2][4];
    #pragma unroll
    for (int i = 0; i < 2; i++)
        #pragma unroll
        for (int j = 0; j < 4; j++)
            #pragma unroll
            for (int r = 0; r < 4; r++) acc[i][j][r] = 0.0f;

    for (int kt = 0; kt < Dn; kt += 64) {
        __syncthreads();
        // A: inline LayerNorm + hi/lo bf16 split
        {
            float g8[8], b8[8];
            *(float4*)&g8[0] = *(const float4*)&gamma[kt + ac8];
            *(float4*)&g8[4] = *(const float4*)&gamma[kt + ac8 + 4];
            *(float4*)&b8[0] = *(const float4*)&beta[kt + ac8];
            *(float4*)&b8[4] = *(const float4*)&beta[kt + ac8 + 4];
            #pragma unroll
            for (int rr = 0; rr < 2; rr++) {
                const int row = r0 + ar0 + rr * 32;
                const float2 st = rr ? st1 : st0;
                float xv[8];
                *(float4*)&xv[0] = *(const float4*)&X[(size_t)row * Dn + kt + ac8];
                *(float4*)&xv[4] = *(const float4*)&X[(size_t)row * Dn + kt + ac8 + 4];
                s8v hv, lv;
                #pragma unroll
                for (int e = 0; e < 8; e++) {
                    float xn = (xv[e] - st.x) * st.y * g8[e] + b8[e];
                    unsigned short h = f2bf(xn);
                    hv[e] = (short)h;
                    lv[e] = (short)f2bf(xn - bf2f(h));
                }
                *(s8v*)&Ah[(ar0 + rr * 32) * BSTR + ac8] = hv;
                *(s8v*)&Al[(ar0 + rr * 32) * BSTR + ac8] = lv;
            }
        }
        #pragma unroll
        for (int ss = 0; ss < 4; ss++) {
            const int row = ar0 + ss * 32;
            *(s8v*)&Bh[row * BSTR + ac8] = *(const s8v*)&Ph[(size_t)(m0 + row) * Dn + kt + ac8];
            *(s8v*)&Bl[row * BSTR + ac8] = *(const s8v*)&Pl[(size_t)(m0 + row) * Dn + kt + ac8];
        }
        __syncthreads();
        #pragma unroll
        for (int ks = 0; ks < 2; ks++) {
            s8v ah[2], al[2], bh[4], bl[4];
            #pragma unroll
            for (int i = 0; i < 2; i++) {
                const int m = wr * 32 + i * 16 + cc;
                ah[i] = *(const s8v*)&Ah[m * BSTR + ks * 32 + quad * 8];
                al[i] = *(const s8v*)&Al[m * BSTR + ks * 32 + quad * 8];
            }
            #pragma unroll
            for (int j = 0; j < 4; j++) {
                const int n = wc * 64 + j * 16 + cc;
                bh[j] = *(const s8v*)&Bh[n * BSTR + ks * 32 + quad * 8];
                bl[j] = *(const s8v*)&Bl[n * BSTR + ks * 32 + quad * 8];
            }
            #pragma unroll
            for (int i = 0; i < 2; i++)
                #pragma unroll
                for (int j = 0; j < 4; j++) {
                    acc[i][j] = __builtin_amdgcn_mfma_f32_16x16x32_bf16(ah[i], bh[j], acc[i][j], 0, 0, 0);
                    acc[i][j] = __builtin_amdgcn_mfma_f32_16x16x32_bf16(ah[i], bl[j], acc[i][j], 0, 0, 0);
                    acc[i][j] = __builtin_amdgcn_mfma_f32_16x16x32_bf16(al[i], bh[j], acc[i][j], 0, 0, 0);
                }
        }
    }
    float rmax[2][4];
    #pragma unroll
    for (int i = 0; i < 2; i++)
        #pragma unroll
        for (int r = 0; r < 4; r++) rmax[i][r] = -INFINITY;
    #pragma unroll
    for (int i = 0; i < 2; i++) {
        const int row = r0 + wr * 32 + i * 16 + quad * 4;
        #pragma unroll
        for (int j = 0; j < 4; j++) {
            const int col = m0 + wc * 64 + j * 16 + cc;
            #pragma unroll
            for (int r = 0; r < 4; r++) {
                float v = DATA_NORM * acc[i][j][r];
                PD[(size_t)(row + r) * Mn + col] = v;
                rmax[i][r] = fmaxf(rmax[i][r], v);
            }
        }
    }
    #pragma unroll
    for (int i = 0; i < 2; i++)
        #pragma unroll
        for (int r = 0; r < 4; r++) {
            float v = rmax[i][r];
            v = fmaxf(v, __shfl_xor(v, 1));
            v = fmaxf(v, __shfl_xor(v, 2));
            v = fmaxf(v, __shfl_xor(v, 4));
            v = fmaxf(v, __shfl_xor(v, 8));
            if (cc == 0)
                atomicMax(&mxqI[r0 + wr * 32 + i * 16 + quad * 4 + r], enc_f(v));
        }
    // batch max: block max -> one atomicMax per block
    float bm = fmaxf(fmaxf(rmax[0][0], rmax[0][1]), fmaxf(rmax[0][2], rmax[0][3]));
    bm = fmaxf(bm, fmaxf(fmaxf(rmax[1][0], rmax[1][1]), fmaxf(rmax[1][2], rmax[1][3])));
    #pragma unroll
    for (int o = 32; o > 0; o >>= 1) bm = fmaxf(bm, __shfl_xor(bm, o));
    if (lane == 0) bmS[w] = bm;
    __syncthreads();
    if (t == 0)
        atomicMax(&mxkI[r0 >> 12], enc_f(fmaxf(fmaxf(bmS[0], bmS[1]), fmaxf(bmS[2], bmS[3]))));
}

// ---------- 4. features: z<4 -> K (bf16 KT transposed + ksum) AND Q (bf16 row-major);
// ----------           z>=4 -> V transpose (inline-LN from X -> bf16 VT) ----------
__global__ __launch_bounds__(256) void k_featvt(const float* __restrict__ PD,
                                                const float* __restrict__ X,
                                                const float2* __restrict__ stats,
                                                const float* __restrict__ gamma,
                                                const float* __restrict__ beta,
                                                const float* __restrict__ diag,
                                                const unsigned* __restrict__ mxkI,
                                                const unsigned* __restrict__ mxqI,
                                                unsigned short* __restrict__ KT,
                                                unsigned short* __restrict__ QR,
                                                unsigned short* __restrict__ VT,
                                                float* __restrict__ KSUM) {
    const int s0 = blockIdx.x * 64, c0 = blockIdx.y * 64, z = blockIdx.z;
    const int t = threadIdx.x;
    const int sr = t >> 2, cc16 = (t & 3) * 16;
    if (z < 4) {
        __shared__ float T[64][65];
        const int b = z;
        const int gr = b * Sn + s0 + sr;
        const float mk = dec_f(mxkI[b]);
        const float dmv = diag[gr] + mk;
        const float srow = __expf(mk - dec_f(mxqI[gr]));   // exp(mxk - mxq_row) >= 1
        const float* p = PD + (size_t)gr * Mn + c0 + cc16;
        float v[16];
        *(float4*)&v[0]  = *(const float4*)&p[0];
        *(float4*)&v[4]  = *(const float4*)&p[4];
        *(float4*)&v[8]  = *(const float4*)&p[8];
        *(float4*)&v[12] = *(const float4*)&p[12];
        s8v q0, q1;
        #pragma unroll
        for (int e = 0; e < 16; e++) {
            float ev = __expf(v[e] - dmv);
            T[cc16 + e][sr] = RATIO * (ev + KEPS);                 // k feature (fp32 for KT)
            unsigned short qb = f2bf(RATIO * (ev * srow + KEPS));  // exact q feature
            if (e < 8) q0[e] = (short)qb; else q1[e - 8] = (short)qb;
        }
        *(s8v*)&QR[(size_t)gr * Mn + c0 + cc16]     = q0;
        *(s8v*)&QR[(size_t)gr * Mn + c0 + cc16 + 8] = q1;
        __syncthreads();
        const int ml = t >> 2, sc = (t & 3) * 16;
        float ks = 0.0f;
        s8v o0, o1;
        #pragma unroll
        for (int i = 0; i < 8; i++) {
            float f0 = T[ml][sc + i], f1 = T[ml][sc + 8 + i];
            ks += f0 + f1;
            o0[i] = (short)f2bf(f0);
            o1[i] = (short)f2bf(f1);
        }
        unsigned short* q = KT + ((size_t)b * Mn + c0 + ml) * Sn + s0 + sc;
        *(s8v*)&q[0] = o0;
        *(s8v*)&q[8] = o1;
        ks += __shfl_xor(ks, 1);
        ks += __shfl_xor(ks, 2);
        if ((t & 3) == 0) atomicAdd(&KSUM[b * Mn + c0 + ml], ks);
    } else {
        __shared__ unsigned short Tu[64][72];
        const int b = z - 4;
        const int gr = b * Sn + s0 + sr;
        const float2 st = stats[gr];
        const float* xp = X + (size_t)gr * Dn + c0 + cc16;
        float xv[16], g16[16], b16[16];
        *(float4*)&xv[0]  = *(const float4*)&xp[0];
        *(float4*)&xv[4]  = *(const float4*)&xp[4];
        *(float4*)&xv[8]  = *(const float4*)&xp[8];
        *(float4*)&xv[12] = *(const float4*)&xp[12];
        *(float4*)&g16[0]  = *(const float4*)&gamma[c0 + cc16];
        *(float4*)&g16[4]  = *(const float4*)&gamma[c0 + cc16 + 4];
        *(float4*)&g16[8]  = *(const float4*)&gamma[c0 + cc16 + 8];
        *(float4*)&g16[12] = *(const float4*)&gamma[c0 + cc16 + 12];
        *(float4*)&b16[0]  = *(const float4*)&beta[c0 + cc16];
        *(float4*)&b16[4]  = *(const float4*)&beta[c0 + cc16 + 4];
        *(float4*)&b16[8]  = *(const float4*)&beta[c0 + cc16 + 8];
        *(float4*)&b16[12] = *(const float4*)&beta[c0 + cc16 + 12];
        #pragma unroll
        for (int e = 0; e < 16; e++) {
            float xn = (xv[e] - st.x) * st.y * g16[e] + b16[e];
            Tu[cc16 + e][sr] = f2bf(xn);
        }
        __syncthreads();
        const int dl = t >> 2, sc = (t & 3) * 16;
        s8v o0, o1;
        #pragma unroll
        for (int i = 0; i < 8; i++) {
            o0[i] = (short)Tu[dl][sc + i];
            o1[i] = (short)Tu[dl][sc + 8 + i];
        }
        unsigned short* q = VT + ((size_t)b * Dn + c0 + dl) * Sn + s0 + sc;
        *(s8v*)&q[0] = o0;
        *(s8v*)&q[8] = o1;
    }
}

// ---------- 5. GEMM2 (bf16): PART[chunk][b][d][m] = VT_chunk @ KT_chunk^T ----------
// 4 split-K chunks x 16 64x64 tiles x 4 batches = 256 blocks; K=1024 per block.
__global__ __launch_bounds__(256, 2) void k_gemm2(const unsigned short* __restrict__ VT,
                                                  const unsigned short* __restrict__ KT,
                                                  float* __restrict__ PART) {
    __shared__ unsigned short Abuf[64 * BSTR], Bbuf[64 * BSTR];
    const int t = threadIdx.x, lane = t & 63, w = t >> 6;
    const int wr = w >> 1, wc = w & 1, quad = lane >> 4, cc = lane & 15;
    const int chunk = blockIdx.x, til = blockIdx.y, b = blockIdx.z;
    const int d0 = (til >> 2) * 64, m0 = (til & 3) * 64;
    const unsigned short* Ab = VT + ((size_t)b * Dn + d0) * Sn + chunk * 1024;
    const unsigned short* Bb = KT + ((size_t)b * Mn + m0) * Sn + chunk * 1024;
    const int sr = t >> 2, sc = (t & 3) * 16;
    f4v acc[2][2];
    #pragma unroll
    for (int i = 0; i < 2; i++)
        #pragma unroll
        for (int j = 0; j < 2; j++)
            #pragma unroll
            for (int r = 0; r < 4; r++) acc[i][j][r] = 0.0f;

    for (int kt = 0; kt < 1024; kt += 64) {
        __syncthreads();
        *(s8v*)&Abuf[sr * BSTR + sc]     = *(const s8v*)&Ab[(size_t)sr * Sn + kt + sc];
        *(s8v*)&Abuf[sr * BSTR + sc + 8] = *(const s8v*)&Ab[(size_t)sr * Sn + kt + sc + 8];
        *(s8v*)&Bbuf[sr * BSTR + sc]     = *(const s8v*)&Bb[(size_t)sr * Sn + kt + sc];
        *(s8v*)&Bbuf[sr * BSTR + sc + 8] = *(const s8v*)&Bb[(size_t)sr * Sn + kt + sc + 8];
        __syncthreads();
        #pragma unroll
        for (int ks = 0; ks < 2; ks++) {
            s8v a[2], bb[2];
            #pragma unroll
            for (int i = 0; i < 2; i++)
                a[i] = *(const s8v*)&Abuf[(wr * 32 + i * 16 + cc) * BSTR + ks * 32 + quad * 8];
            #pragma unroll
            for (int j = 0; j < 2; j++)
                bb[j] = *(const s8v*)&Bbuf[(wc * 32 + j * 16 + cc) * BSTR + ks * 32 + quad * 8];
            #pragma unroll
            for (int i = 0; i < 2; i++)
                #pragma unroll
                for (int j = 0; j < 2; j++)
                    acc[i][j] = __builtin_amdgcn_mfma_f32_16x16x32_bf16(a[i], bb[j], acc[i][j], 0, 0, 0);
        }
    }
    float* dst = PART + (size_t)(chunk * Bn + b) * (Dn * Mn);
    #pragma unroll
    for (int i = 0; i < 2; i++) {
        const int drow = d0 + wr * 32 + i * 16 + quad * 4;
        #pragma unroll
        for (int j = 0; j < 2; j++) {
            const int col = m0 + wc * 32 + j * 16 + cc;
            #pragma unroll
            for (int r = 0; r < 4; r++)
                dst[(size_t)(drow + r) * Mn + col] = acc[i][j][r];
        }
    }
}

// ---------- 6. reduce 4 split-K partials -> CT bf16 [b][d][m] ----------
__global__ __launch_bounds__(256) void k_ctxred(const float* __restrict__ PART,
                                                unsigned short* __restrict__ CT) {
    const int g = blockIdx.x * 256 + threadIdx.x;   // 65536 float4 groups
    float4 s = make_float4(0.f, 0.f, 0.f, 0.f);
    #pragma unroll
    for (int c = 0; c < 4; c++) {
        float4 p = *(const float4*)&PART[(size_t)c * 262144 + (size_t)g * 4];
        s.x += p.x; s.y += p.y; s.z += p.z; s.w += p.w;
    }
    s4v o;
    o[0] = (short)f2bf(s.x); o[1] = (short)f2bf(s.y);
    o[2] = (short)f2bf(s.z); o[3] = (short)f2bf(s.w);
    *(s4v*)&CT[(size_t)g * 4] = o;
}

// ---------- 7. GEMM3 (pure bf16): out = (QR @ CT^T) * dinv, qks in staging, 8-head write ----------
// 64x128 tile, BK=64, grid 512. Epilogue: LDS transpose -> float4 stores.
__global__ __launch_bounds__(256, 2) void k_gemm3(const unsigned short* __restrict__ QR,
                                                  const unsigned short* __restrict__ CT,
                                                  const float* __restrict__ KSUM,
                                                  float* __restrict__ OUT) {
    __shared__ unsigned short Abuf[64 * BSTR], Bbuf[128 * BSTR];
    __shared__ float kslds[Mn];
    __shared__ float dinvS[64];
    __shared__ float OutS[64][136];   // 136: float4-aligned rows, 2-way bank aliasing (free)
    const int t = threadIdx.x, lane = t & 63, w = t >> 6;
    const int wr = w >> 1, wc = w & 1, quad = lane >> 4, cc = lane & 15;
    const int r0 = blockIdx.x * 64, d0 = blockIdx.y * 128;
    const int b = r0 >> 12;
    kslds[t] = KSUM[b * Mn + t];
    const int ar0 = t >> 3, ac8 = (t & 7) * 8;
    float qks0 = 0.0f, qks1 = 0.0f;
    f4v acc[2][4];
    #pragma unroll
    for (int i = 0; i < 2; i++)
        #pragma unroll
        for (int j = 0; j < 4; j++)
            #pragma unroll
            for (int r = 0; r < 4; r++) acc[i][j][r] = 0.0f;

    for (int kt = 0; kt < Mn; kt += 64) {
        __syncthreads();   // covers kslds on first iteration
        s8v a0 = *(const s8v*)&QR[(size_t)(r0 + ar0) * Mn + kt + ac8];
        s8v a1 = *(const s8v*)&QR[(size_t)(r0 + ar0 + 32) * Mn + kt + ac8];
        *(s8v*)&Abuf[ar0 * BSTR + ac8]        = a0;
        *(s8v*)&Abuf[(ar0 + 32) * BSTR + ac8] = a1;
        #pragma unroll
        for (int e = 0; e < 8; e++) {
            const float ks = kslds[kt + ac8 + e];
            qks0 += bf2f((unsigned short)a0[e]) * ks;
            qks1 += bf2f((unsigned short)a1[e]) * ks;
        }
        #pragma unroll
        for (int ss = 0; ss < 4; ss++) {
            const int row = ar0 + ss * 32;
            *(s8v*)&Bbuf[row * BSTR + ac8] =
                *(const s8v*)&CT[((size_t)b * Dn + d0 + row) * Mn + kt + ac8];
        }
        __syncthreads();
        #pragma unroll
        for (int ks = 0; ks < 2; ks++) {
            s8v a[2], bb[4];
            #pragma unroll
            for (int i = 0; i < 2; i++)
                a[i] = *(const s8v*)&Abuf[(wr * 32 + i * 16 + cc) * BSTR + ks * 32 + quad * 8];
            #pragma unroll
            for (int j = 0; j < 4; j++)
                bb[j] = *(const s8v*)&Bbuf[(wc * 64 + j * 16 + cc) * BSTR + ks * 32 + quad * 8];
            #pragma unroll
            for (int i = 0; i < 2; i++)
                #pragma unroll
                for (int j = 0; j < 4; j++)
                    acc[i][j] = __builtin_amdgcn_mfma_f32_16x16x32_bf16(a[i], bb[j], acc[i][j], 0, 0, 0);
        }
    }
    qks0 += __shfl_xor(qks0, 1); qks0 += __shfl_xor(qks0, 2); qks0 += __shfl_xor(qks0, 4);
    qks1 += __shfl_xor(qks1, 1); qks1 += __shfl_xor(qks1, 2); qks1 += __shfl_xor(qks1, 4);
    if ((t & 7) == 0) {
        dinvS[ar0]      = 1.0f / qks0;
        dinvS[ar0 + 32] = 1.0f / qks1;
    }
    __syncthreads();
    // stage scaled tile into LDS
    #pragma unroll
    for (int i = 0; i < 2; i++) {
        const int rl0 = wr * 32 + i * 16 + quad * 4;
        #pragma unroll
        for (int r = 0; r < 4; r++) {
            const float dv = dinvS[rl0 + r];
            #pragma unroll
            for (int j = 0; j < 4; j++)
                OutS[rl0 + r][wc * 64 + j * 16 + cc] = acc[i][j][r] * dv;
        }
    }
    __syncthreads();
    // cooperative float4 stores: 64 rows x 32 float4; lanes 0..31 of a wave cover 512 B contiguous
    const int rb = t >> 5;            // 0..7
    const int c4 = (t & 31) * 4;      // 0..124
    #pragma unroll
    for (int it = 0; it < 8; it++) {
        const int row = it * 8 + rb;
        float4 v = *(const float4*)&OutS[row][c4];
        const int gr = r0 + row;
        const int ss = gr & (Sn - 1);
        const size_t basep = ((size_t)(b * Hn) * Sn + ss) * Dn + d0 + c4;
        #pragma unroll
        for (int h = 0; h < Hn; h++)
            *(float4*)&OUT[basep + (size_t)h * Sn * Dn] = v;
    }
}

extern "C" void kernel_launch(void* const* d_in, const int* in_sizes, int n_in,
                              void* d_out, int out_size, void* d_ws, size_t ws_size,
                              hipStream_t stream) {
    const float* X     = (const float*)d_in[0];
    const float* gamma = (const float*)d_in[1];
    const float* beta  = (const float*)d_in[2];
    const float* P     = (const float*)d_in[3];
    float* OUT = (float*)d_out;

    char* base = (char*)d_ws;
    float*          PD   = (float*)(base);                       // 16,777,216 (PART alias)
    unsigned short* QR   = (unsigned short*)(base + 16777216);   //  8,388,608
    unsigned short* VT   = (unsigned short*)(base + 25165824);   //  8,388,608
    unsigned short* KT   = (unsigned short*)(base + 33554432);   //  8,388,608
    unsigned short* CT   = (unsigned short*)(base + 41943040);   //    524,288
    unsigned short* Ph   = (unsigned short*)(base + 42467328);   //    131,072
    unsigned short* Pl   = (unsigned short*)(base + 42598400);   //    131,072
    float2*         stats= (float2*)(base + 42729472);           //    131,072
    float*          diag = (float*)(base + 42860544);            //     65,536
    unsigned*       mxqI = (unsigned*)(base + 42926080);         //     65,536
    unsigned*       mxkI = (unsigned*)(base + 42991616);         //         16
    float*          KSUM = (float*)(base + 42991680);            //      4,096
    float*          PART = PD;    // alias: PD dead after featvt (4 chunks x 1 MB = 4 MB used)

    k_ln<<<BSn / 4 + 33, 256, 0, stream>>>(X, gamma, beta, P, stats, diag, mxqI, Ph, Pl, KSUM, mxkI);
    k_gemm1<<<dim3(BSn / 64, Mn / 128), 256, 0, stream>>>(X, stats, gamma, beta, Ph, Pl, PD, mxqI, mxkI);
    k_featvt<<<dim3(Sn / 64, 4, 8), 256, 0, stream>>>(PD, X, stats, gamma, beta, diag, mxkI, mxqI, KT, QR, VT, KSUM);
    k_gemm2<<<dim3(4, 16, Bn), 256, 0, stream>>>(VT, KT, PART);
    k_ctxred<<<256, 256, 0, stream>>>(PART, CT);
    k_gemm3<<<dim3(BSn / 64, Dn / 128), 256, 0, stream>>>(QR, CT, KSUM, OUT);
}

// Round 3
// 201.075 us; speedup vs baseline: 1.0321x; 1.0321x over previous
//
#include <hip/hip_runtime.h>
#include <math.h>

// Problem constants (fixed by setup_inputs)
#define Bn 4
#define Hn 8
#define Sn 4096
#define Dn 256
#define Mn 256
#define BSn (Bn*Sn)          // 16384 rows
#define LN_EPS 1e-5f
#define KEPS 1e-4f
#define DATA_NORM 0.25f      // 256^-0.25
#define RATIO 0.0625f        // 256^-0.5

typedef short s8v __attribute__((ext_vector_type(8)));   // 8 bf16 (4 VGPRs)
typedef short s4v __attribute__((ext_vector_type(4)));
typedef float f4v __attribute__((ext_vector_type(4)));   // MFMA acc

#define BSTR 72   // bf16 BK=64 LDS row stride, shorts (144 B rows -> 2-way bank aliasing, free)

// ---------- bf16 helpers (manual RNE) ----------
__device__ __forceinline__ unsigned short f2bf(float x) {
    unsigned u = __float_as_uint(x);
    u += 0x7FFFu + ((u >> 16) & 1u);
    return (unsigned short)(u >> 16);
}
__device__ __forceinline__ float bf2f(unsigned short h) {
    return __uint_as_float(((unsigned)h) << 16);
}
// monotone float<->uint encoding for atomicMax rowmax (0 acts as sentinel below all data)
__device__ __forceinline__ unsigned enc_f(float f) {
    unsigned u = __float_as_uint(f);
    return (u & 0x80000000u) ? ~u : (u | 0x80000000u);
}
__device__ __forceinline__ float dec_f(unsigned u) {
    unsigned b = (u & 0x80000000u) ? (u ^ 0x80000000u) : ~u;
    return __uint_as_float(b);
}

// ---------- 1. LayerNorm (wave-per-row) -> split XNh/XNl + diag + mxqI zero ----------
// Extra blocks (>= BSn/4): split P into hi/lo bf16, zero KSUM, zero mxkI.
__global__ __launch_bounds__(256) void k_ln(const float* __restrict__ X,
                                            const float* __restrict__ gamma,
                                            const float* __restrict__ beta,
                                            const float* __restrict__ P,
                                            unsigned short* __restrict__ XNh,
                                            unsigned short* __restrict__ XNl,
                                            unsigned short* __restrict__ Ph,
                                            unsigned short* __restrict__ Pl,
                                            float* __restrict__ diag,
                                            unsigned* __restrict__ mxqI,
                                            float* __restrict__ KSUM,
                                            unsigned* __restrict__ mxkI) {
    if (blockIdx.x >= BSn / 4) {
        const int e = blockIdx.x - BSn / 4;
        if (e < 32) {
            // split P into hi/lo bf16
            const int i = (e * 256 + threadIdx.x) * 8;
            float v[8];
            *(float4*)&v[0] = *(const float4*)&P[i];
            *(float4*)&v[4] = *(const float4*)&P[i + 4];
            s8v hh, ll;
            #pragma unroll
            for (int q = 0; q < 8; q++) {
                unsigned short h = f2bf(v[q]);
                hh[q] = (short)h;
                ll[q] = (short)f2bf(v[q] - bf2f(h));
            }
            *(s8v*)&Ph[i] = hh;
            *(s8v*)&Pl[i] = ll;
        } else {
            KSUM[threadIdx.x]       = 0.0f;
            KSUM[threadIdx.x + 256] = 0.0f;
            KSUM[threadIdx.x + 512] = 0.0f;
            KSUM[threadIdx.x + 768] = 0.0f;
            if (threadIdx.x < 4) mxkI[threadIdx.x] = 0u;
        }
        return;
    }
    const int w = threadIdx.x >> 6, l = threadIdx.x & 63;
    const int row = blockIdx.x * 4 + w;
    float4 x = *(const float4*)&X[(size_t)row * Dn + l * 4];
    float s = x.x + x.y + x.z + x.w;
    #pragma unroll
    for (int o = 32; o > 0; o >>= 1) s += __shfl_xor(s, o);
    const float mean = s * (1.0f / Dn);
    float xn[4] = {x.x - mean, x.y - mean, x.z - mean, x.w - mean};
    float vs = xn[0] * xn[0] + xn[1] * xn[1] + xn[2] * xn[2] + xn[3] * xn[3];
    #pragma unroll
    for (int o = 32; o > 0; o >>= 1) vs += __shfl_xor(vs, o);
    const float rs = rsqrtf(vs * (1.0f / Dn) + LN_EPS);
    float4 g = *(const float4*)&gamma[l * 4];
    float4 bt = *(const float4*)&beta[l * 4];
    xn[0] = xn[0] * rs * g.x + bt.x;
    xn[1] = xn[1] * rs * g.y + bt.y;
    xn[2] = xn[2] * rs * g.z + bt.z;
    xn[3] = xn[3] * rs * g.w + bt.w;
    s4v hv, lv;
    float d2 = 0.0f;
    #pragma unroll
    for (int c = 0; c < 4; c++) {
        d2 += xn[c] * xn[c];
        unsigned short h = f2bf(xn[c]);
        hv[c] = (short)h;
        lv[c] = (short)f2bf(xn[c] - bf2f(h));
    }
    *(s4v*)&XNh[(size_t)row * Dn + l * 4] = hv;
    *(s4v*)&XNl[(size_t)row * Dn + l * 4] = lv;
    #pragma unroll
    for (int o = 32; o > 0; o >>= 1) d2 += __shfl_xor(d2, o);
    if (l == 0) { diag[row] = 0.03125f * d2; mxqI[row] = 0u; }
}

// ---------- 2. GEMM1 (split fp32, pre-split operands): PD = 0.25*XN@P^T + rowmax + batchmax ----------
// 64x128 tile, BK=64, grid 512 (2 blocks/CU). Staging = pure b128 copies.
__global__ __launch_bounds__(256, 2) void k_gemm1(const unsigned short* __restrict__ XNh,
                                                  const unsigned short* __restrict__ XNl,
                                                  const unsigned short* __restrict__ Ph,
                                                  const unsigned short* __restrict__ Pl,
                                                  float* __restrict__ PD,
                                                  unsigned* __restrict__ mxqI,
                                                  unsigned* __restrict__ mxkI) {
    __shared__ unsigned short Ah[64 * BSTR], Al[64 * BSTR];
    __shared__ unsigned short Bh[128 * BSTR], Bl[128 * BSTR];
    __shared__ float bmS[4];
    const int t = threadIdx.x, lane = t & 63, w = t >> 6;
    const int wr = w >> 1, wc = w & 1, quad = lane >> 4, cc = lane & 15;
    const int r0 = blockIdx.x * 64, m0 = blockIdx.y * 128;
    const int ar0 = t >> 3, ac8 = (t & 7) * 8;
    f4v acc[2][4];
    #pragma unroll
    for (int i = 0; i < 2; i++)
        #pragma unroll
        for (int j = 0; j < 4; j++)
            #pragma unroll
            for (int r = 0; r < 4; r++) acc[i][j][r] = 0.0f;

    for (int kt = 0; kt < Dn; kt += 64) {
        __syncthreads();
        *(s8v*)&Ah[ar0 * BSTR + ac8]        = *(const s8v*)&XNh[(size_t)(r0 + ar0) * Dn + kt + ac8];
        *(s8v*)&Al[ar0 * BSTR + ac8]        = *(const s8v*)&XNl[(size_t)(r0 + ar0) * Dn + kt + ac8];
        *(s8v*)&Ah[(ar0 + 32) * BSTR + ac8] = *(const s8v*)&XNh[(size_t)(r0 + ar0 + 32) * Dn + kt + ac8];
        *(s8v*)&Al[(ar0 + 32) * BSTR + ac8] = *(const s8v*)&XNl[(size_t)(r0 + ar0 + 32) * Dn + kt + ac8];
        #pragma unroll
        for (int ss = 0; ss < 4; ss++) {
            const int row = ar0 + ss * 32;
            *(s8v*)&Bh[row * BSTR + ac8] = *(const s8v*)&Ph[(size_t)(m0 + row) * Dn + kt + ac8];
            *(s8v*)&Bl[row * BSTR + ac8] = *(const s8v*)&Pl[(size_t)(m0 + row) * Dn + kt + ac8];
        }
        __syncthreads();
        #pragma unroll
        for (int ks = 0; ks < 2; ks++) {
            s8v ah[2], al[2], bh[4], bl[4];
            #pragma unroll
            for (int i = 0; i < 2; i++) {
                const int m = wr * 32 + i * 16 + cc;
                ah[i] = *(const s8v*)&Ah[m * BSTR + ks * 32 + quad * 8];
                al[i] = *(const s8v*)&Al[m * BSTR + ks * 32 + quad * 8];
            }
            #pragma unroll
            for (int j = 0; j < 4; j++) {
                const int n = wc * 64 + j * 16 + cc;
                bh[j] = *(const s8v*)&Bh[n * BSTR + ks * 32 + quad * 8];
                bl[j] = *(const s8v*)&Bl[n * BSTR + ks * 32 + quad * 8];
            }
            #pragma unroll
            for (int i = 0; i < 2; i++)
                #pragma unroll
                for (int j = 0; j < 4; j++) {
                    acc[i][j] = __builtin_amdgcn_mfma_f32_16x16x32_bf16(ah[i], bh[j], acc[i][j], 0, 0, 0);
                    acc[i][j] = __builtin_amdgcn_mfma_f32_16x16x32_bf16(ah[i], bl[j], acc[i][j], 0, 0, 0);
                    acc[i][j] = __builtin_amdgcn_mfma_f32_16x16x32_bf16(al[i], bh[j], acc[i][j], 0, 0, 0);
                }
        }
    }
    float rmax[2][4];
    #pragma unroll
    for (int i = 0; i < 2; i++)
        #pragma unroll
        for (int r = 0; r < 4; r++) rmax[i][r] = -INFINITY;
    #pragma unroll
    for (int i = 0; i < 2; i++) {
        const int row = r0 + wr * 32 + i * 16 + quad * 4;
        #pragma unroll
        for (int j = 0; j < 4; j++) {
            const int col = m0 + wc * 64 + j * 16 + cc;
            #pragma unroll
            for (int r = 0; r < 4; r++) {
                float v = DATA_NORM * acc[i][j][r];
                PD[(size_t)(row + r) * Mn + col] = v;
                rmax[i][r] = fmaxf(rmax[i][r], v);
            }
        }
    }
    #pragma unroll
    for (int i = 0; i < 2; i++)
        #pragma unroll
        for (int r = 0; r < 4; r++) {
            float v = rmax[i][r];
            v = fmaxf(v, __shfl_xor(v, 1));
            v = fmaxf(v, __shfl_xor(v, 2));
            v = fmaxf(v, __shfl_xor(v, 4));
            v = fmaxf(v, __shfl_xor(v, 8));
            if (cc == 0)
                atomicMax(&mxqI[r0 + wr * 32 + i * 16 + quad * 4 + r], enc_f(v));
        }
    // batch max: block max -> one atomicMax per block
    float bm = fmaxf(fmaxf(rmax[0][0], rmax[0][1]), fmaxf(rmax[0][2], rmax[0][3]));
    bm = fmaxf(bm, fmaxf(fmaxf(rmax[1][0], rmax[1][1]), fmaxf(rmax[1][2], rmax[1][3])));
    #pragma unroll
    for (int o = 32; o > 0; o >>= 1) bm = fmaxf(bm, __shfl_xor(bm, o));
    if (lane == 0) bmS[w] = bm;
    __syncthreads();
    if (t == 0)
        atomicMax(&mxkI[r0 >> 12], enc_f(fmaxf(fmaxf(bmS[0], bmS[1]), fmaxf(bmS[2], bmS[3]))));
}

// ---------- 4. features: K (bf16 KT transposed + ksum) AND Q (bf16 row-major) ----------
// V-transpose half eliminated: gemm2 now stages V^T directly from XNh.
__global__ __launch_bounds__(256) void k_featvt(const float* __restrict__ PD,
                                                const float* __restrict__ diag,
                                                const unsigned* __restrict__ mxkI,
                                                const unsigned* __restrict__ mxqI,
                                                unsigned short* __restrict__ KT,
                                                unsigned short* __restrict__ QR,
                                                float* __restrict__ KSUM) {
    const int s0 = blockIdx.x * 64, c0 = blockIdx.y * 64, b = blockIdx.z;
    const int t = threadIdx.x;
    const int sr = t >> 2, cc16 = (t & 3) * 16;
    __shared__ float T[64][65];
    const int gr = b * Sn + s0 + sr;
    const float mk = dec_f(mxkI[b]);
    const float dmv = diag[gr] + mk;
    const float srow = __expf(mk - dec_f(mxqI[gr]));   // exp(mxk - mxq_row) >= 1
    const float* p = PD + (size_t)gr * Mn + c0 + cc16;
    float v[16];
    *(float4*)&v[0]  = *(const float4*)&p[0];
    *(float4*)&v[4]  = *(const float4*)&p[4];
    *(float4*)&v[8]  = *(const float4*)&p[8];
    *(float4*)&v[12] = *(const float4*)&p[12];
    s8v q0, q1;
    #pragma unroll
    for (int e = 0; e < 16; e++) {
        float ev = __expf(v[e] - dmv);
        T[cc16 + e][sr] = RATIO * (ev + KEPS);                 // k feature (fp32 for KT)
        unsigned short qb = f2bf(RATIO * (ev * srow + KEPS));  // exact q feature
        if (e < 8) q0[e] = (short)qb; else q1[e - 8] = (short)qb;
    }
    *(s8v*)&QR[(size_t)gr * Mn + c0 + cc16]     = q0;
    *(s8v*)&QR[(size_t)gr * Mn + c0 + cc16 + 8] = q1;
    __syncthreads();
    const int ml = t >> 2, sc = (t & 3) * 16;
    float ks = 0.0f;
    s8v o0, o1;
    #pragma unroll
    for (int i = 0; i < 8; i++) {
        float f0 = T[ml][sc + i], f1 = T[ml][sc + 8 + i];
        ks += f0 + f1;
        o0[i] = (short)f2bf(f0);
        o1[i] = (short)f2bf(f1);
    }
    unsigned short* q = KT + ((size_t)b * Mn + c0 + ml) * Sn + s0 + sc;
    *(s8v*)&q[0] = o0;
    *(s8v*)&q[8] = o1;
    ks += __shfl_xor(ks, 1);
    ks += __shfl_xor(ks, 2);
    if ((t & 3) == 0) atomicAdd(&KSUM[b * Mn + c0 + ml], ks);
}

// ---------- 5. GEMM2 (bf16): PART[chunk][b][d][m] = LN(X)h^T_chunk @ KT_chunk^T ----------
// 8 split-K chunks x 16 64x64 tiles x 4 batches = 512 blocks (2/CU); K=512 per block.
// A is staged DIRECTLY from row-major XNh via in-LDS transpose with XOR block-swizzle
// on the s-index (8-aligned -> b128 reads stay contiguous; writes hit 32 banks 2-way = free).
__global__ __launch_bounds__(256, 2) void k_gemm2(const unsigned short* __restrict__ XNh,
                                                  const unsigned short* __restrict__ KT,
                                                  float* __restrict__ PART) {
    __shared__ unsigned short Abuf[64 * BSTR], Bbuf[64 * BSTR];
    const int t = threadIdx.x, lane = t & 63, w = t >> 6;
    const int wr = w >> 1, wc = w & 1, quad = lane >> 4, cc = lane & 15;
    const int chunk = blockIdx.x, til = blockIdx.y, b = blockIdx.z;
    const int d0 = (til >> 2) * 64, m0 = (til & 3) * 64;
    const int sr = t >> 2, sc = (t & 3) * 16;
    const int dc = (t & 3) * 16;                 // d-column base for transposed A staging
    f4v acc[2][2];
    #pragma unroll
    for (int i = 0; i < 2; i++)
        #pragma unroll
        for (int j = 0; j < 2; j++)
            #pragma unroll
            for (int r = 0; r < 4; r++) acc[i][j][r] = 0.0f;

    // per-lane XOR swizzle amounts for the MFMA A reads (dloc = wr*32 + i*16 + cc)
    int aswz[2];
    #pragma unroll
    for (int i = 0; i < 2; i++)
        aswz[i] = ((((wr * 32 + i * 16 + cc) >> 3) & 7) << 3);

    for (int kt = 0; kt < 512; kt += 64) {
        __syncthreads();
        // A: transposed stage from XNh. thread reads 16 d of one s-row, scatters b16 into LDS.
        {
            const int gs = chunk * 512 + kt + sr;               // global s
            const unsigned short* xp = &XNh[((size_t)b * Sn + gs) * Dn + d0 + dc];
            s8v x0 = *(const s8v*)&xp[0];
            s8v x1 = *(const s8v*)&xp[8];
            #pragma unroll
            for (int e = 0; e < 8; e++) {
                const int dl0 = dc + e, dl1 = dc + 8 + e;
                Abuf[dl0 * BSTR + (sr ^ (((dl0 >> 3) & 7) << 3))] = (unsigned short)x0[e];
                Abuf[dl1 * BSTR + (sr ^ (((dl1 >> 3) & 7) << 3))] = (unsigned short)x1[e];
            }
        }
        // B: linear copy from KT (already [m][s])
        {
            const unsigned short* bp = &KT[((size_t)b * Mn + m0 + sr) * Sn + chunk * 512 + kt + sc];
            *(s8v*)&Bbuf[sr * BSTR + sc]     = *(const s8v*)&bp[0];
            *(s8v*)&Bbuf[sr * BSTR + sc + 8] = *(const s8v*)&bp[8];
        }
        __syncthreads();
        #pragma unroll
        for (int ks = 0; ks < 2; ks++) {
            s8v a[2], bb[2];
            #pragma unroll
            for (int i = 0; i < 2; i++)
                a[i] = *(const s8v*)&Abuf[(wr * 32 + i * 16 + cc) * BSTR + ((ks * 32 + quad * 8) ^ aswz[i])];
            #pragma unroll
            for (int j = 0; j < 2; j++)
                bb[j] = *(const s8v*)&Bbuf[(wc * 32 + j * 16 + cc) * BSTR + ks * 32 + quad * 8];
            #pragma unroll
            for (int i = 0; i < 2; i++)
                #pragma unroll
                for (int j = 0; j < 2; j++)
                    acc[i][j] = __builtin_amdgcn_mfma_f32_16x16x32_bf16(a[i], bb[j], acc[i][j], 0, 0, 0);
        }
    }
    float* dst = PART + (size_t)(chunk * Bn + b) * (Dn * Mn);
    #pragma unroll
    for (int i = 0; i < 2; i++) {
        const int drow = d0 + wr * 32 + i * 16 + quad * 4;
        #pragma unroll
        for (int j = 0; j < 2; j++) {
            const int col = m0 + wc * 32 + j * 16 + cc;
            #pragma unroll
            for (int r = 0; r < 4; r++)
                dst[(size_t)(drow + r) * Mn + col] = acc[i][j][r];
        }
    }
}

// ---------- 6. reduce 8 split-K partials -> CT bf16 [b][d][m] ----------
__global__ __launch_bounds__(256) void k_ctxred(const float* __restrict__ PART,
                                                unsigned short* __restrict__ CT) {
    const int g = blockIdx.x * 256 + threadIdx.x;   // 65536 float4 groups
    float4 s = make_float4(0.f, 0.f, 0.f, 0.f);
    #pragma unroll
    for (int c = 0; c < 8; c++) {
        float4 p = *(const float4*)&PART[(size_t)c * 262144 + (size_t)g * 4];
        s.x += p.x; s.y += p.y; s.z += p.z; s.w += p.w;
    }
    s4v o;
    o[0] = (short)f2bf(s.x); o[1] = (short)f2bf(s.y);
    o[2] = (short)f2bf(s.z); o[3] = (short)f2bf(s.w);
    *(s4v*)&CT[(size_t)g * 4] = o;
}

// ---------- 7. GEMM3 (pure bf16): out = (QR @ CT^T) * dinv, qks in staging, 8-head write ----------
// 64x128 tile, BK=64, grid 512. Epilogue: LDS transpose -> float4 stores.
__global__ __launch_bounds__(256, 2) void k_gemm3(const unsigned short* __restrict__ QR,
                                                  const unsigned short* __restrict__ CT,
                                                  const float* __restrict__ KSUM,
                                                  float* __restrict__ OUT) {
    __shared__ unsigned short Abuf[64 * BSTR], Bbuf[128 * BSTR];
    __shared__ float kslds[Mn];
    __shared__ float dinvS[64];
    __shared__ float OutS[64][136];   // 136: float4-aligned rows, 2-way bank aliasing (free)
    const int t = threadIdx.x, lane = t & 63, w = t >> 6;
    const int wr = w >> 1, wc = w & 1, quad = lane >> 4, cc = lane & 15;
    const int r0 = blockIdx.x * 64, d0 = blockIdx.y * 128;
    const int b = r0 >> 12;
    kslds[t] = KSUM[b * Mn + t];
    const int ar0 = t >> 3, ac8 = (t & 7) * 8;
    float qks0 = 0.0f, qks1 = 0.0f;
    f4v acc[2][4];
    #pragma unroll
    for (int i = 0; i < 2; i++)
        #pragma unroll
        for (int j = 0; j < 4; j++)
            #pragma unroll
            for (int r = 0; r < 4; r++) acc[i][j][r] = 0.0f;

    for (int kt = 0; kt < Mn; kt += 64) {
        __syncthreads();   // covers kslds on first iteration
        s8v a0 = *(const s8v*)&QR[(size_t)(r0 + ar0) * Mn + kt + ac8];
        s8v a1 = *(const s8v*)&QR[(size_t)(r0 + ar0 + 32) * Mn + kt + ac8];
        *(s8v*)&Abuf[ar0 * BSTR + ac8]        = a0;
        *(s8v*)&Abuf[(ar0 + 32) * BSTR + ac8] = a1;
        #pragma unroll
        for (int e = 0; e < 8; e++) {
            const float ks = kslds[kt + ac8 + e];
            qks0 += bf2f((unsigned short)a0[e]) * ks;
            qks1 += bf2f((unsigned short)a1[e]) * ks;
        }
        #pragma unroll
        for (int ss = 0; ss < 4; ss++) {
            const int row = ar0 + ss * 32;
            *(s8v*)&Bbuf[row * BSTR + ac8] =
                *(const s8v*)&CT[((size_t)b * Dn + d0 + row) * Mn + kt + ac8];
        }
        __syncthreads();
        #pragma unroll
        for (int ks = 0; ks < 2; ks++) {
            s8v a[2], bb[4];
            #pragma unroll
            for (int i = 0; i < 2; i++)
                a[i] = *(const s8v*)&Abuf[(wr * 32 + i * 16 + cc) * BSTR + ks * 32 + quad * 8];
            #pragma unroll
            for (int j = 0; j < 4; j++)
                bb[j] = *(const s8v*)&Bbuf[(wc * 64 + j * 16 + cc) * BSTR + ks * 32 + quad * 8];
            #pragma unroll
            for (int i = 0; i < 2; i++)
                #pragma unroll
                for (int j = 0; j < 4; j++)
                    acc[i][j] = __builtin_amdgcn_mfma_f32_16x16x32_bf16(a[i], bb[j], acc[i][j], 0, 0, 0);
        }
    }
    qks0 += __shfl_xor(qks0, 1); qks0 += __shfl_xor(qks0, 2); qks0 += __shfl_xor(qks0, 4);
    qks1 += __shfl_xor(qks1, 1); qks1 += __shfl_xor(qks1, 2); qks1 += __shfl_xor(qks1, 4);
    if ((t & 7) == 0) {
        dinvS[ar0]      = 1.0f / qks0;
        dinvS[ar0 + 32] = 1.0f / qks1;
    }
    __syncthreads();
    // stage scaled tile into LDS
    #pragma unroll
    for (int i = 0; i < 2; i++) {
        const int rl0 = wr * 32 + i * 16 + quad * 4;
        #pragma unroll
        for (int r = 0; r < 4; r++) {
            const float dv = dinvS[rl0 + r];
            #pragma unroll
            for (int j = 0; j < 4; j++)
                OutS[rl0 + r][wc * 64 + j * 16 + cc] = acc[i][j][r] * dv;
        }
    }
    __syncthreads();
    // cooperative float4 stores: 64 rows x 32 float4; lanes 0..31 of a wave cover 512 B contiguous
    const int rb = t >> 5;            // 0..7
    const int c4 = (t & 31) * 4;      // 0..124
    #pragma unroll
    for (int it = 0; it < 8; it++) {
        const int row = it * 8 + rb;
        float4 v = *(const float4*)&OutS[row][c4];
        const int gr = r0 + row;
        const int ss = gr & (Sn - 1);
        const size_t basep = ((size_t)(b * Hn) * Sn + ss) * Dn + d0 + c4;
        #pragma unroll
        for (int h = 0; h < Hn; h++)
            *(float4*)&OUT[basep + (size_t)h * Sn * Dn] = v;
    }
}

extern "C" void kernel_launch(void* const* d_in, const int* in_sizes, int n_in,
                              void* d_out, int out_size, void* d_ws, size_t ws_size,
                              hipStream_t stream) {
    const float* X     = (const float*)d_in[0];
    const float* gamma = (const float*)d_in[1];
    const float* beta  = (const float*)d_in[2];
    const float* P     = (const float*)d_in[3];
    float* OUT = (float*)d_out;

    char* base = (char*)d_ws;
    unsigned short* XNh = (unsigned short*)(base);               //  8,388,608 B (live through gemm2)
    unsigned short* XNl = (unsigned short*)(base + 8388608);     //  8,388,608 (dead after gemm1 -> KT)
    float*          PD  = (float*)(base + 16777216);             // 16,777,216 (dead after featvt -> PART 8MB)
    unsigned short* QR  = (unsigned short*)(base + 33554432);    //  8,388,608
    unsigned short* CT  = (unsigned short*)(base + 41943040);    //    524,288
    unsigned short* Ph  = (unsigned short*)(base + 42467328);    //    131,072
    unsigned short* Pl  = (unsigned short*)(base + 42598400);    //    131,072
    float*          diag = (float*)(base + 42729472);            //     65,536
    unsigned*       mxqI = (unsigned*)(base + 42795008);         //     65,536
    unsigned*       mxkI = (unsigned*)(base + 42860544);         //         16
    float*          KSUM = (float*)(base + 42860608);            //      4,096
    unsigned short* KT   = XNl;   // alias: XNl dead after gemm1
    float*          PART = PD;    // alias: PD dead after featvt (8 chunks x 1 MB)

    k_ln<<<BSn / 4 + 33, 256, 0, stream>>>(X, gamma, beta, P, XNh, XNl, Ph, Pl, diag, mxqI, KSUM, mxkI);
    k_gemm1<<<dim3(BSn / 64, Mn / 128), 256, 0, stream>>>(XNh, XNl, Ph, Pl, PD, mxqI, mxkI);
    k_featvt<<<dim3(Sn / 64, 4, 4), 256, 0, stream>>>(PD, diag, mxkI, mxqI, KT, QR, KSUM);
    k_gemm2<<<dim3(8, 16, Bn), 256, 0, stream>>>(XNh, KT, PART);
    k_ctxred<<<256, 256, 0, stream>>>(PART, CT);
    k_gemm3<<<dim3(BSn / 64, Dn / 128), 256, 0, stream>>>(QR, CT, KSUM, OUT);
}

// Round 4
// 197.834 us; speedup vs baseline: 1.0490x; 1.0164x over previous
//
#include <hip/hip_runtime.h>
#include <math.h>

// Problem constants (fixed by setup_inputs)
#define Bn 4
#define Hn 8
#define Sn 4096
#define Dn 256
#define Mn 256
#define BSn (Bn*Sn)          // 16384 rows
#define LN_EPS 1e-5f
#define KEPS 1e-4f
#define DATA_NORM 0.25f      // 256^-0.25
#define RATIO 0.0625f        // 256^-0.5

typedef short s8v __attribute__((ext_vector_type(8)));   // 8 bf16 (4 VGPRs)
typedef short s4v __attribute__((ext_vector_type(4)));
typedef float f4v __attribute__((ext_vector_type(4)));   // MFMA acc

#define BSTR 72   // bf16 BK=64 LDS row stride, shorts (144 B rows -> 2-way bank aliasing, free)

// ---------- bf16 helpers (manual RNE) ----------
__device__ __forceinline__ unsigned short f2bf(float x) {
    unsigned u = __float_as_uint(x);
    u += 0x7FFFu + ((u >> 16) & 1u);
    return (unsigned short)(u >> 16);
}
__device__ __forceinline__ float bf2f(unsigned short h) {
    return __uint_as_float(((unsigned)h) << 16);
}
// monotone float<->uint encoding for atomicMax rowmax (0 acts as sentinel below all data)
__device__ __forceinline__ unsigned enc_f(float f) {
    unsigned u = __float_as_uint(f);
    return (u & 0x80000000u) ? ~u : (u | 0x80000000u);
}
__device__ __forceinline__ float dec_f(unsigned u) {
    unsigned b = (u & 0x80000000u) ? (u ^ 0x80000000u) : ~u;
    return __uint_as_float(b);
}

// ---------- 1. LayerNorm (wave-per-row) -> split XNh/XNl + diag + mxqI zero ----------
// Extra blocks (>= BSn/4): split P into hi/lo bf16, zero KSUM, zero mxkI.
__global__ __launch_bounds__(256) void k_ln(const float* __restrict__ X,
                                            const float* __restrict__ gamma,
                                            const float* __restrict__ beta,
                                            const float* __restrict__ P,
                                            unsigned short* __restrict__ XNh,
                                            unsigned short* __restrict__ XNl,
                                            unsigned short* __restrict__ Ph,
                                            unsigned short* __restrict__ Pl,
                                            float* __restrict__ diag,
                                            unsigned* __restrict__ mxqI,
                                            float* __restrict__ KSUM,
                                            unsigned* __restrict__ mxkI) {
    if (blockIdx.x >= BSn / 4) {
        const int e = blockIdx.x - BSn / 4;
        if (e < 32) {
            // split P into hi/lo bf16
            const int i = (e * 256 + threadIdx.x) * 8;
            float v[8];
            *(float4*)&v[0] = *(const float4*)&P[i];
            *(float4*)&v[4] = *(const float4*)&P[i + 4];
            s8v hh, ll;
            #pragma unroll
            for (int q = 0; q < 8; q++) {
                unsigned short h = f2bf(v[q]);
                hh[q] = (short)h;
                ll[q] = (short)f2bf(v[q] - bf2f(h));
            }
            *(s8v*)&Ph[i] = hh;
            *(s8v*)&Pl[i] = ll;
        } else {
            KSUM[threadIdx.x]       = 0.0f;
            KSUM[threadIdx.x + 256] = 0.0f;
            KSUM[threadIdx.x + 512] = 0.0f;
            KSUM[threadIdx.x + 768] = 0.0f;
            if (threadIdx.x < 4) mxkI[threadIdx.x] = 0u;
        }
        return;
    }
    const int w = threadIdx.x >> 6, l = threadIdx.x & 63;
    const int row = blockIdx.x * 4 + w;
    float4 x = *(const float4*)&X[(size_t)row * Dn + l * 4];
    float s = x.x + x.y + x.z + x.w;
    #pragma unroll
    for (int o = 32; o > 0; o >>= 1) s += __shfl_xor(s, o);
    const float mean = s * (1.0f / Dn);
    float xn[4] = {x.x - mean, x.y - mean, x.z - mean, x.w - mean};
    float vs = xn[0] * xn[0] + xn[1] * xn[1] + xn[2] * xn[2] + xn[3] * xn[3];
    #pragma unroll
    for (int o = 32; o > 0; o >>= 1) vs += __shfl_xor(vs, o);
    const float rs = rsqrtf(vs * (1.0f / Dn) + LN_EPS);
    float4 g = *(const float4*)&gamma[l * 4];
    float4 bt = *(const float4*)&beta[l * 4];
    xn[0] = xn[0] * rs * g.x + bt.x;
    xn[1] = xn[1] * rs * g.y + bt.y;
    xn[2] = xn[2] * rs * g.z + bt.z;
    xn[3] = xn[3] * rs * g.w + bt.w;
    s4v hv, lv;
    float d2 = 0.0f;
    #pragma unroll
    for (int c = 0; c < 4; c++) {
        d2 += xn[c] * xn[c];
        unsigned short h = f2bf(xn[c]);
        hv[c] = (short)h;
        lv[c] = (short)f2bf(xn[c] - bf2f(h));
    }
    *(s4v*)&XNh[(size_t)row * Dn + l * 4] = hv;
    *(s4v*)&XNl[(size_t)row * Dn + l * 4] = lv;
    #pragma unroll
    for (int o = 32; o > 0; o >>= 1) d2 += __shfl_xor(d2, o);
    if (l == 0) { diag[row] = 0.03125f * d2; mxqI[row] = 0u; }
}

// ---------- 2. GEMM1 (split fp32, pre-split operands): PD = 0.25*XN@P^T + rowmax + batchmax ----------
// 64x128 tile, BK=64, grid 512 (2 blocks/CU). Prefetch next K-tile into regs before MFMA
// so global-load latency hides under the MFMA cluster (T14 async-stage split).
__global__ __launch_bounds__(256, 2) void k_gemm1(const unsigned short* __restrict__ XNh,
                                                  const unsigned short* __restrict__ XNl,
                                                  const unsigned short* __restrict__ Ph,
                                                  const unsigned short* __restrict__ Pl,
                                                  float* __restrict__ PD,
                                                  unsigned* __restrict__ mxqI,
                                                  unsigned* __restrict__ mxkI) {
    __shared__ unsigned short Ah[64 * BSTR], Al[64 * BSTR];
    __shared__ unsigned short Bh[128 * BSTR], Bl[128 * BSTR];
    __shared__ float bmS[4];
    const int t = threadIdx.x, lane = t & 63, w = t >> 6;
    const int wr = w >> 1, wc = w & 1, quad = lane >> 4, cc = lane & 15;
    const int r0 = blockIdx.x * 64, m0 = blockIdx.y * 128;
    const int ar0 = t >> 3, ac8 = (t & 7) * 8;
    f4v acc[2][4];
    #pragma unroll
    for (int i = 0; i < 2; i++)
        #pragma unroll
        for (int j = 0; j < 4; j++)
            #pragma unroll
            for (int r = 0; r < 4; r++) acc[i][j][r] = 0.0f;

    s8v rAh0, rAl0, rAh1, rAl1, rBh[4], rBl[4];
    const unsigned short* pAh0 = &XNh[(size_t)(r0 + ar0) * Dn + ac8];
    const unsigned short* pAl0 = &XNl[(size_t)(r0 + ar0) * Dn + ac8];
    const unsigned short* pAh1 = &XNh[(size_t)(r0 + ar0 + 32) * Dn + ac8];
    const unsigned short* pAl1 = &XNl[(size_t)(r0 + ar0 + 32) * Dn + ac8];
    const unsigned short* pB   = &Ph[(size_t)(m0 + ar0) * Dn + ac8];
    const unsigned short* pBl  = &Pl[(size_t)(m0 + ar0) * Dn + ac8];

#define G1LOAD(KT)                                                              \
    do {                                                                        \
        rAh0 = *(const s8v*)&pAh0[KT];                                          \
        rAl0 = *(const s8v*)&pAl0[KT];                                          \
        rAh1 = *(const s8v*)&pAh1[KT];                                          \
        rAl1 = *(const s8v*)&pAl1[KT];                                          \
        _Pragma("unroll")                                                       \
        for (int ss = 0; ss < 4; ss++) {                                        \
            rBh[ss] = *(const s8v*)&pB[(size_t)ss * 32 * Dn + (KT)];            \
            rBl[ss] = *(const s8v*)&pBl[(size_t)ss * 32 * Dn + (KT)];           \
        }                                                                       \
    } while (0)

    G1LOAD(0);
    for (int kt = 0; kt < Dn; kt += 64) {
        __syncthreads();   // previous MFMA done reading LDS
        *(s8v*)&Ah[ar0 * BSTR + ac8]        = rAh0;
        *(s8v*)&Al[ar0 * BSTR + ac8]        = rAl0;
        *(s8v*)&Ah[(ar0 + 32) * BSTR + ac8] = rAh1;
        *(s8v*)&Al[(ar0 + 32) * BSTR + ac8] = rAl1;
        #pragma unroll
        for (int ss = 0; ss < 4; ss++) {
            *(s8v*)&Bh[(ar0 + ss * 32) * BSTR + ac8] = rBh[ss];
            *(s8v*)&Bl[(ar0 + ss * 32) * BSTR + ac8] = rBl[ss];
        }
        __syncthreads();
        if (kt + 64 < Dn) G1LOAD(kt + 64);   // latency hides under MFMA below
        #pragma unroll
        for (int ks = 0; ks < 2; ks++) {
            s8v ah[2], al[2], bh[4], bl[4];
            #pragma unroll
            for (int i = 0; i < 2; i++) {
                const int m = wr * 32 + i * 16 + cc;
                ah[i] = *(const s8v*)&Ah[m * BSTR + ks * 32 + quad * 8];
                al[i] = *(const s8v*)&Al[m * BSTR + ks * 32 + quad * 8];
            }
            #pragma unroll
            for (int j = 0; j < 4; j++) {
                const int n = wc * 64 + j * 16 + cc;
                bh[j] = *(const s8v*)&Bh[n * BSTR + ks * 32 + quad * 8];
                bl[j] = *(const s8v*)&Bl[n * BSTR + ks * 32 + quad * 8];
            }
            #pragma unroll
            for (int i = 0; i < 2; i++)
                #pragma unroll
                for (int j = 0; j < 4; j++) {
                    acc[i][j] = __builtin_amdgcn_mfma_f32_16x16x32_bf16(ah[i], bh[j], acc[i][j], 0, 0, 0);
                    acc[i][j] = __builtin_amdgcn_mfma_f32_16x16x32_bf16(ah[i], bl[j], acc[i][j], 0, 0, 0);
                    acc[i][j] = __builtin_amdgcn_mfma_f32_16x16x32_bf16(al[i], bh[j], acc[i][j], 0, 0, 0);
                }
        }
    }
#undef G1LOAD
    float rmax[2][4];
    #pragma unroll
    for (int i = 0; i < 2; i++)
        #pragma unroll
        for (int r = 0; r < 4; r++) rmax[i][r] = -INFINITY;
    #pragma unroll
    for (int i = 0; i < 2; i++) {
        const int row = r0 + wr * 32 + i * 16 + quad * 4;
        #pragma unroll
        for (int j = 0; j < 4; j++) {
            const int col = m0 + wc * 64 + j * 16 + cc;
            #pragma unroll
            for (int r = 0; r < 4; r++) {
                float v = DATA_NORM * acc[i][j][r];
                PD[(size_t)(row + r) * Mn + col] = v;
                rmax[i][r] = fmaxf(rmax[i][r], v);
            }
        }
    }
    #pragma unroll
    for (int i = 0; i < 2; i++)
        #pragma unroll
        for (int r = 0; r < 4; r++) {
            float v = rmax[i][r];
            v = fmaxf(v, __shfl_xor(v, 1));
            v = fmaxf(v, __shfl_xor(v, 2));
            v = fmaxf(v, __shfl_xor(v, 4));
            v = fmaxf(v, __shfl_xor(v, 8));
            if (cc == 0)
                atomicMax(&mxqI[r0 + wr * 32 + i * 16 + quad * 4 + r], enc_f(v));
        }
    // batch max: block max -> one atomicMax per block
    float bm = fmaxf(fmaxf(rmax[0][0], rmax[0][1]), fmaxf(rmax[0][2], rmax[0][3]));
    bm = fmaxf(bm, fmaxf(fmaxf(rmax[1][0], rmax[1][1]), fmaxf(rmax[1][2], rmax[1][3])));
    #pragma unroll
    for (int o = 32; o > 0; o >>= 1) bm = fmaxf(bm, __shfl_xor(bm, o));
    if (lane == 0) bmS[w] = bm;
    __syncthreads();
    if (t == 0)
        atomicMax(&mxkI[r0 >> 12], enc_f(fmaxf(fmaxf(bmS[0], bmS[1]), fmaxf(bmS[2], bmS[3]))));
}

// ---------- 4. features: K (bf16 KT transposed + ksum) AND Q (bf16 row-major) ----------
// V-transpose half eliminated: gemm2 stages V^T directly from XNh.
__global__ __launch_bounds__(256) void k_featvt(const float* __restrict__ PD,
                                                const float* __restrict__ diag,
                                                const unsigned* __restrict__ mxkI,
                                                const unsigned* __restrict__ mxqI,
                                                unsigned short* __restrict__ KT,
                                                unsigned short* __restrict__ QR,
                                                float* __restrict__ KSUM) {
    const int s0 = blockIdx.x * 64, c0 = blockIdx.y * 64, b = blockIdx.z;
    const int t = threadIdx.x;
    const int sr = t >> 2, cc16 = (t & 3) * 16;
    __shared__ float T[64][65];
    const int gr = b * Sn + s0 + sr;
    const float mk = dec_f(mxkI[b]);
    const float dmv = diag[gr] + mk;
    const float srow = __expf(mk - dec_f(mxqI[gr]));   // exp(mxk - mxq_row) >= 1
    const float* p = PD + (size_t)gr * Mn + c0 + cc16;
    float v[16];
    *(float4*)&v[0]  = *(const float4*)&p[0];
    *(float4*)&v[4]  = *(const float4*)&p[4];
    *(float4*)&v[8]  = *(const float4*)&p[8];
    *(float4*)&v[12] = *(const float4*)&p[12];
    s8v q0, q1;
    #pragma unroll
    for (int e = 0; e < 16; e++) {
        float ev = __expf(v[e] - dmv);
        T[cc16 + e][sr] = RATIO * (ev + KEPS);                 // k feature (fp32 for KT)
        unsigned short qb = f2bf(RATIO * (ev * srow + KEPS));  // exact q feature
        if (e < 8) q0[e] = (short)qb; else q1[e - 8] = (short)qb;
    }
    *(s8v*)&QR[(size_t)gr * Mn + c0 + cc16]     = q0;
    *(s8v*)&QR[(size_t)gr * Mn + c0 + cc16 + 8] = q1;
    __syncthreads();
    const int ml = t >> 2, sc = (t & 3) * 16;
    float ks = 0.0f;
    s8v o0, o1;
    #pragma unroll
    for (int i = 0; i < 8; i++) {
        float f0 = T[ml][sc + i], f1 = T[ml][sc + 8 + i];
        ks += f0 + f1;
        o0[i] = (short)f2bf(f0);
        o1[i] = (short)f2bf(f1);
    }
    unsigned short* q = KT + ((size_t)b * Mn + c0 + ml) * Sn + s0 + sc;
    *(s8v*)&q[0] = o0;
    *(s8v*)&q[8] = o1;
    ks += __shfl_xor(ks, 1);
    ks += __shfl_xor(ks, 2);
    if ((t & 3) == 0) atomicAdd(&KSUM[b * Mn + c0 + ml], ks);
}

// ---------- 5. GEMM2 (bf16): PART[chunk][b][d][m] = LN(X)h^T_chunk @ KT_chunk^T ----------
// 8 split-K chunks x 16 64x64 tiles x 4 batches = 512 blocks (2/CU); K=512 per block.
// A staged directly from row-major XNh via in-LDS transpose (XOR s-swizzle, conflict-free).
// Prefetch next K-tile into regs before MFMA.
__global__ __launch_bounds__(256, 2) void k_gemm2(const unsigned short* __restrict__ XNh,
                                                  const unsigned short* __restrict__ KT,
                                                  float* __restrict__ PART) {
    __shared__ unsigned short Abuf[64 * BSTR], Bbuf[64 * BSTR];
    const int t = threadIdx.x, lane = t & 63, w = t >> 6;
    const int wr = w >> 1, wc = w & 1, quad = lane >> 4, cc = lane & 15;
    const int chunk = blockIdx.x, til = blockIdx.y, b = blockIdx.z;
    const int d0 = (til >> 2) * 64, m0 = (til & 3) * 64;
    const int sr = t >> 2, sc = (t & 3) * 16;
    const int dc = (t & 3) * 16;                 // d-column base for transposed A staging
    f4v acc[2][2];
    #pragma unroll
    for (int i = 0; i < 2; i++)
        #pragma unroll
        for (int j = 0; j < 2; j++)
            #pragma unroll
            for (int r = 0; r < 4; r++) acc[i][j][r] = 0.0f;

    // per-lane XOR swizzle amounts for the MFMA A reads (dloc = wr*32 + i*16 + cc)
    int aswz[2];
    #pragma unroll
    for (int i = 0; i < 2; i++)
        aswz[i] = ((((wr * 32 + i * 16 + cc) >> 3) & 7) << 3);

    const unsigned short* pA = &XNh[((size_t)b * Sn + chunk * 512 + sr) * Dn + d0 + dc];
    const unsigned short* pB = &KT[((size_t)b * Mn + m0 + sr) * Sn + chunk * 512 + sc];

    s8v rx0, rx1, rb0, rb1;
#define G2LOAD(KT_)                                                 \
    do {                                                            \
        rx0 = *(const s8v*)&pA[(size_t)(KT_) * Dn];                 \
        rx1 = *(const s8v*)&pA[(size_t)(KT_) * Dn + 8];             \
        rb0 = *(const s8v*)&pB[KT_];                                \
        rb1 = *(const s8v*)&pB[(KT_) + 8];                          \
    } while (0)

    G2LOAD(0);
    for (int kt = 0; kt < 512; kt += 64) {
        __syncthreads();
        // A: transposed scatter (b16) with XOR swizzle on s
        #pragma unroll
        for (int e = 0; e < 8; e++) {
            const int dl0 = dc + e, dl1 = dc + 8 + e;
            Abuf[dl0 * BSTR + (sr ^ (((dl0 >> 3) & 7) << 3))] = (unsigned short)rx0[e];
            Abuf[dl1 * BSTR + (sr ^ (((dl1 >> 3) & 7) << 3))] = (unsigned short)rx1[e];
        }
        // B: linear copy
        *(s8v*)&Bbuf[sr * BSTR + sc]     = rb0;
        *(s8v*)&Bbuf[sr * BSTR + sc + 8] = rb1;
        __syncthreads();
        if (kt + 64 < 512) G2LOAD(kt + 64);   // latency hides under MFMA
        #pragma unroll
        for (int ks = 0; ks < 2; ks++) {
            s8v a[2], bb[2];
            #pragma unroll
            for (int i = 0; i < 2; i++)
                a[i] = *(const s8v*)&Abuf[(wr * 32 + i * 16 + cc) * BSTR + ((ks * 32 + quad * 8) ^ aswz[i])];
            #pragma unroll
            for (int j = 0; j < 2; j++)
                bb[j] = *(const s8v*)&Bbuf[(wc * 32 + j * 16 + cc) * BSTR + ks * 32 + quad * 8];
            #pragma unroll
            for (int i = 0; i < 2; i++)
                #pragma unroll
                for (int j = 0; j < 2; j++)
                    acc[i][j] = __builtin_amdgcn_mfma_f32_16x16x32_bf16(a[i], bb[j], acc[i][j], 0, 0, 0);
        }
    }
#undef G2LOAD
    float* dst = PART + (size_t)(chunk * Bn + b) * (Dn * Mn);
    #pragma unroll
    for (int i = 0; i < 2; i++) {
        const int drow = d0 + wr * 32 + i * 16 + quad * 4;
        #pragma unroll
        for (int j = 0; j < 2; j++) {
            const int col = m0 + wc * 32 + j * 16 + cc;
            #pragma unroll
            for (int r = 0; r < 4; r++)
                dst[(size_t)(drow + r) * Mn + col] = acc[i][j][r];
        }
    }
}

// ---------- 6. reduce 8 split-K partials -> CT bf16 [b][d][m] ----------
__global__ __launch_bounds__(256) void k_ctxred(const float* __restrict__ PART,
                                                unsigned short* __restrict__ CT) {
    const int g = blockIdx.x * 256 + threadIdx.x;   // 65536 float4 groups
    float4 s = make_float4(0.f, 0.f, 0.f, 0.f);
    #pragma unroll
    for (int c = 0; c < 8; c++) {
        float4 p = *(const float4*)&PART[(size_t)c * 262144 + (size_t)g * 4];
        s.x += p.x; s.y += p.y; s.z += p.z; s.w += p.w;
    }
    s4v o;
    o[0] = (short)f2bf(s.x); o[1] = (short)f2bf(s.y);
    o[2] = (short)f2bf(s.z); o[3] = (short)f2bf(s.w);
    *(s4v*)&CT[(size_t)g * 4] = o;
}

// ---------- 7. GEMM3 (pure bf16): out = (QR @ CT^T) * dinv, qks in staging, 8-head write ----------
// 64x128 tile, BK=64, grid 512. Prefetch next K-tile into regs; LDS-transpose epilogue.
__global__ __launch_bounds__(256, 2) void k_gemm3(const unsigned short* __restrict__ QR,
                                                  const unsigned short* __restrict__ CT,
                                                  const float* __restrict__ KSUM,
                                                  float* __restrict__ OUT) {
    __shared__ unsigned short Abuf[64 * BSTR], Bbuf[128 * BSTR];
    __shared__ float kslds[Mn];
    __shared__ float dinvS[64];
    __shared__ float OutS[64][136];   // 136: float4-aligned rows, 2-way bank aliasing (free)
    const int t = threadIdx.x, lane = t & 63, w = t >> 6;
    const int wr = w >> 1, wc = w & 1, quad = lane >> 4, cc = lane & 15;
    const int r0 = blockIdx.x * 64, d0 = blockIdx.y * 128;
    const int b = r0 >> 12;
    kslds[t] = KSUM[b * Mn + t];
    const int ar0 = t >> 3, ac8 = (t & 7) * 8;
    float qks0 = 0.0f, qks1 = 0.0f;
    f4v acc[2][4];
    #pragma unroll
    for (int i = 0; i < 2; i++)
        #pragma unroll
        for (int j = 0; j < 4; j++)
            #pragma unroll
            for (int r = 0; r < 4; r++) acc[i][j][r] = 0.0f;

    const unsigned short* pA0 = &QR[(size_t)(r0 + ar0) * Mn + ac8];
    const unsigned short* pA1 = &QR[(size_t)(r0 + ar0 + 32) * Mn + ac8];
    const unsigned short* pBb = &CT[((size_t)b * Dn + d0 + ar0) * Mn + ac8];

    s8v a0, a1, rb[4];
#define G3LOAD(KT_)                                                     \
    do {                                                                \
        a0 = *(const s8v*)&pA0[KT_];                                    \
        a1 = *(const s8v*)&pA1[KT_];                                    \
        _Pragma("unroll")                                               \
        for (int ss = 0; ss < 4; ss++)                                  \
            rb[ss] = *(const s8v*)&pBb[(size_t)ss * 32 * Mn + (KT_)];   \
    } while (0)

    G3LOAD(0);
    for (int kt = 0; kt < Mn; kt += 64) {
        __syncthreads();   // covers kslds on first iteration
        *(s8v*)&Abuf[ar0 * BSTR + ac8]        = a0;
        *(s8v*)&Abuf[(ar0 + 32) * BSTR + ac8] = a1;
        #pragma unroll
        for (int ss = 0; ss < 4; ss++)
            *(s8v*)&Bbuf[(ar0 + ss * 32) * BSTR + ac8] = rb[ss];
        #pragma unroll
        for (int e = 0; e < 8; e++) {
            const float ks = kslds[kt + ac8 + e];
            qks0 += bf2f((unsigned short)a0[e]) * ks;
            qks1 += bf2f((unsigned short)a1[e]) * ks;
        }
        __syncthreads();
        if (kt + 64 < Mn) G3LOAD(kt + 64);   // latency hides under MFMA
        #pragma unroll
        for (int ks = 0; ks < 2; ks++) {
            s8v a[2], bb[4];
            #pragma unroll
            for (int i = 0; i < 2; i++)
                a[i] = *(const s8v*)&Abuf[(wr * 32 + i * 16 + cc) * BSTR + ks * 32 + quad * 8];
            #pragma unroll
            for (int j = 0; j < 4; j++)
                bb[j] = *(const s8v*)&Bbuf[(wc * 64 + j * 16 + cc) * BSTR + ks * 32 + quad * 8];
            #pragma unroll
            for (int i = 0; i < 2; i++)
                #pragma unroll
                for (int j = 0; j < 4; j++)
                    acc[i][j] = __builtin_amdgcn_mfma_f32_16x16x32_bf16(a[i], bb[j], acc[i][j], 0, 0, 0);
        }
    }
#undef G3LOAD
    qks0 += __shfl_xor(qks0, 1); qks0 += __shfl_xor(qks0, 2); qks0 += __shfl_xor(qks0, 4);
    qks1 += __shfl_xor(qks1, 1); qks1 += __shfl_xor(qks1, 2); qks1 += __shfl_xor(qks1, 4);
    if ((t & 7) == 0) {
        dinvS[ar0]      = 1.0f / qks0;
        dinvS[ar0 + 32] = 1.0f / qks1;
    }
    __syncthreads();
    // stage scaled tile into LDS
    #pragma unroll
    for (int i = 0; i < 2; i++) {
        const int rl0 = wr * 32 + i * 16 + quad * 4;
        #pragma unroll
        for (int r = 0; r < 4; r++) {
            const float dv = dinvS[rl0 + r];
            #pragma unroll
            for (int j = 0; j < 4; j++)
                OutS[rl0 + r][wc * 64 + j * 16 + cc] = acc[i][j][r] * dv;
        }
    }
    __syncthreads();
    // cooperative float4 stores: 64 rows x 32 float4; lanes 0..31 of a wave cover 512 B contiguous
    const int rb2 = t >> 5;           // 0..7
    const int c4 = (t & 31) * 4;      // 0..124
    #pragma unroll
    for (int it = 0; it < 8; it++) {
        const int row = it * 8 + rb2;
        float4 v = *(const float4*)&OutS[row][c4];
        const int gr = r0 + row;
        const int ss = gr & (Sn - 1);
        const size_t basep = ((size_t)(b * Hn) * Sn + ss) * Dn + d0 + c4;
        #pragma unroll
        for (int h = 0; h < Hn; h++)
            *(float4*)&OUT[basep + (size_t)h * Sn * Dn] = v;
    }
}

extern "C" void kernel_launch(void* const* d_in, const int* in_sizes, int n_in,
                              void* d_out, int out_size, void* d_ws, size_t ws_size,
                              hipStream_t stream) {
    const float* X     = (const float*)d_in[0];
    const float* gamma = (const float*)d_in[1];
    const float* beta  = (const float*)d_in[2];
    const float* P     = (const float*)d_in[3];
    float* OUT = (float*)d_out;

    char* base = (char*)d_ws;
    unsigned short* XNh = (unsigned short*)(base);               //  8,388,608 B (live through gemm2)
    unsigned short* XNl = (unsigned short*)(base + 8388608);     //  8,388,608 (dead after gemm1 -> KT)
    float*          PD  = (float*)(base + 16777216);             // 16,777,216 (dead after featvt -> PART 8MB)
    unsigned short* QR  = (unsigned short*)(base + 33554432);    //  8,388,608
    unsigned short* CT  = (unsigned short*)(base + 41943040);    //    524,288
    unsigned short* Ph  = (unsigned short*)(base + 42467328);    //    131,072
    unsigned short* Pl  = (unsigned short*)(base + 42598400);    //    131,072
    float*          diag = (float*)(base + 42729472);            //     65,536
    unsigned*       mxqI = (unsigned*)(base + 42795008);         //     65,536
    unsigned*       mxkI = (unsigned*)(base + 42860544);         //         16
    float*          KSUM = (float*)(base + 42860608);            //      4,096
    unsigned short* KT   = XNl;   // alias: XNl dead after gemm1
    float*          PART = PD;    // alias: PD dead after featvt (8 chunks x 1 MB)

    k_ln<<<BSn / 4 + 33, 256, 0, stream>>>(X, gamma, beta, P, XNh, XNl, Ph, Pl, diag, mxqI, KSUM, mxkI);
    k_gemm1<<<dim3(BSn / 64, Mn / 128), 256, 0, stream>>>(XNh, XNl, Ph, Pl, PD, mxqI, mxkI);
    k_featvt<<<dim3(Sn / 64, 4, 4), 256, 0, stream>>>(PD, diag, mxkI, mxqI, KT, QR, KSUM);
    k_gemm2<<<dim3(8, 16, Bn), 256, 0, stream>>>(XNh, KT, PART);
    k_ctxred<<<256, 256, 0, stream>>>(PART, CT);
    k_gemm3<<<dim3(BSn / 64, Dn / 128), 256, 0, stream>>>(QR, CT, KSUM, OUT);
}